// Round 11
// baseline (510.001 us; speedup 1.0000x reference)
//
#include <hip/hip_runtime.h>

#define ALPHA 0.9f
#define BETA  0.8f
#define K     25
#define B     128
#define T     16
#define IN_DIM 14400
#define NSL   8      // batch slices (= XCDs)
#define SW    16     // batch elems per slice
// Paired-t row: [feature][2][16] = 128B line; lanes 0-3 t-even, 4-7 t-odd.

// ---------------------------------------------------------------------------
// Transpose one 8-t slab of x (B,T,IN) -> xTh[4tp][8e][IN][2][16].
// ---------------------------------------------------------------------------
__global__ __launch_bounds__(256) void transpose_pair_kernel(
    const float* __restrict__ x, float* __restrict__ xTh, int t0) {
  __shared__ float tile[64][65];
  const int tl = blockIdx.z;            // local t 0..7
  const int t  = t0 + tl;
  const int i0 = blockIdx.x * 64;       // feature tile
  const int b0 = blockIdx.y * 64;       // batch tile
  const int tid = threadIdx.x;

  const int fi = (tid & 15) * 4;        // feature quad
  const int bi = tid >> 4;              // batch row 0..15
#pragma unroll
  for (int p = 0; p < 4; ++p) {
    const int b = bi + p * 16;
    const float4 v = *(const float4*)&x[(size_t)(b0 + b) * (T * IN_DIM) +
                                        (size_t)t * IN_DIM + i0 + fi];
    tile[fi + 0][b] = v.x;
    tile[fi + 1][b] = v.y;
    tile[fi + 2][b] = v.z;
    tile[fi + 3][b] = v.w;
  }
  __syncthreads();
  const int bq = (tid & 15) * 4;        // batch quad (0,4,..,60)
  const int fr = tid >> 4;              // feature row 0..15
  const int e  = (b0 + bq) >> 4;        // slice
  const int bl = bq & 15;               // 0,4,8,12
#pragma unroll
  for (int p = 0; p < 4; ++p) {
    const int f = fr + p * 16;
    float4 v;
    v.x = tile[f][bq + 0];
    v.y = tile[f][bq + 1];
    v.z = tile[f][bq + 2];
    v.w = tile[f][bq + 3];
    *(float4*)&xTh[(((size_t)(tl >> 1) * NSL + e) * IN_DIM + (i0 + f)) * 32 +
                   (tl & 1) * SW + bl] = v;
  }
}

// ---------------------------------------------------------------------------
// Fused LCN+LIF with t-PAIRED 128B rows. hsrc: [NTP][8][dprev][32],
// memout: [NTP..][8][dim][32], state: [2][8][dim][16].
// Thread layout: 256 thr = 32 neurons x 8 lanes; lane = (half(t-parity), bq).
// Each wave load instr covers 8 full 128B lines, serving TWO timesteps ->
// half the L2 line-requests of the 64B-row layout. LIF pair resolved via
// __shfl_xor(4); both halves redundantly track (s,m). One sched_barrier
// pins a 13-deep load window (data regs are 4/load now, fits 128 VGPR).
// blockIdx%8 = slice = XCD; all grids <= 1024 = residency at 4 blk/CU.
// ---------------------------------------------------------------------------
template <int NTP, int NPASS>
__global__ __launch_bounds__(256, 4) void lcn_pair(
    const float* __restrict__ hsrc, const float* __restrict__ w,
    const float* __restrict__ bias, const int* __restrict__ knn,
    float* __restrict__ memout, float* __restrict__ state,
    int dim, int dprev, int nblk, int load_state, int save_state) {
  const int e    = blockIdx.x & 7;        // slice -> XCD
  const int blk  = blockIdx.x >> 3;
  const int nl   = threadIdx.x >> 3;      // neuron in block (0..31)
  const int l8   = threadIdx.x & 7;
  const int half = l8 >> 2;               // t parity handled by this lane
  const int bq   = (l8 & 3) * 4;          // batch quad

  const size_t row = 32;                  // floats per paired row

#pragma unroll 1
  for (int p = 0; p < NPASS; ++p) {
    const int dd = (blk + p * nblk) * 32 + nl;
    const bool act = dd < dim;
    const int d = act ? dd : dim - 1;

    int   idx[K];
    float wr[K];
#pragma unroll
    for (int k = 0; k < K; ++k) {
      idx[k] = knn[d * K + k] * 32 + half * SW + bq;
      wr[k]  = w[d * K + k];
    }
    const float bi = bias[d];

    float4 s = make_float4(0.f, 0.f, 0.f, 0.f);
    float4 m = make_float4(0.f, 0.f, 0.f, 0.f);
    if (load_state) {
      const size_t so = ((size_t)e * dim + d) * SW + bq;
      s = *(const float4*)&state[so];
      m = *(const float4*)&state[(size_t)NSL * dim * SW + so];
    }

    for (int tp = 0; tp < NTP; ++tp) {
      const float* hp = hsrc + ((size_t)tp * NSL + e) * dprev * row;
      float4 hv[13], hw[12];
#pragma unroll
      for (int j = 0; j < 13; ++j) hv[j] = *(const float4*)&hp[idx[j]];
      __builtin_amdgcn_sched_barrier(0);  // pin: 13 loads in flight first
#pragma unroll
      for (int j = 0; j < 12; ++j) hw[j] = *(const float4*)&hp[idx[13 + j]];
      float4 a0 = make_float4(bi, bi, bi, bi);
      float4 a1 = make_float4(0.f, 0.f, 0.f, 0.f);
#pragma unroll
      for (int j = 0; j < 13; ++j) {
        const float wk = wr[j];
        if (j & 1) {
          a1.x = fmaf(wk, hv[j].x, a1.x);
          a1.y = fmaf(wk, hv[j].y, a1.y);
          a1.z = fmaf(wk, hv[j].z, a1.z);
          a1.w = fmaf(wk, hv[j].w, a1.w);
        } else {
          a0.x = fmaf(wk, hv[j].x, a0.x);
          a0.y = fmaf(wk, hv[j].y, a0.y);
          a0.z = fmaf(wk, hv[j].z, a0.z);
          a0.w = fmaf(wk, hv[j].w, a0.w);
        }
      }
#pragma unroll
      for (int j = 0; j < 12; ++j) {
        const float wk = wr[13 + j];
        if (j & 1) {
          a1.x = fmaf(wk, hw[j].x, a1.x);
          a1.y = fmaf(wk, hw[j].y, a1.y);
          a1.z = fmaf(wk, hw[j].z, a1.z);
          a1.w = fmaf(wk, hw[j].w, a1.w);
        } else {
          a0.x = fmaf(wk, hw[j].x, a0.x);
          a0.y = fmaf(wk, hw[j].y, a0.y);
          a0.z = fmaf(wk, hw[j].z, a0.z);
          a0.w = fmaf(wk, hw[j].w, a0.w);
        }
      }
      float4 acc;
      acc.x = a0.x + a1.x;
      acc.y = a0.y + a1.y;
      acc.z = a0.z + a1.z;
      acc.w = a0.w + a1.w;
      // exchange halves: lane gets the other parity's pre-activation
      float4 oth;
      oth.x = __shfl_xor(acc.x, 4, 64);
      oth.y = __shfl_xor(acc.y, 4, 64);
      oth.z = __shfl_xor(acc.z, 4, 64);
      oth.w = __shfl_xor(acc.w, 4, 64);
      const float4 pre0 = half ? oth : acc;  // t even
      const float4 pre1 = half ? acc : oth;  // t odd
      // LIF t-even (reset from PREVIOUS membrane)
      s.x = ALPHA * s.x + pre0.x;
      s.y = ALPHA * s.y + pre0.y;
      s.z = ALPHA * s.z + pre0.z;
      s.w = ALPHA * s.w + pre0.w;
      float4 meven;
      meven.x = BETA * m.x + s.x - ((m.x > 1.0f) ? 1.0f : 0.0f);
      meven.y = BETA * m.y + s.y - ((m.y > 1.0f) ? 1.0f : 0.0f);
      meven.z = BETA * m.z + s.z - ((m.z > 1.0f) ? 1.0f : 0.0f);
      meven.w = BETA * m.w + s.w - ((m.w > 1.0f) ? 1.0f : 0.0f);
      // LIF t-odd
      s.x = ALPHA * s.x + pre1.x;
      s.y = ALPHA * s.y + pre1.y;
      s.z = ALPHA * s.z + pre1.z;
      s.w = ALPHA * s.w + pre1.w;
      m.x = BETA * meven.x + s.x - ((meven.x > 1.0f) ? 1.0f : 0.0f);
      m.y = BETA * meven.y + s.y - ((meven.y > 1.0f) ? 1.0f : 0.0f);
      m.z = BETA * meven.z + s.z - ((meven.z > 1.0f) ? 1.0f : 0.0f);
      m.w = BETA * meven.w + s.w - ((meven.w > 1.0f) ? 1.0f : 0.0f);
      if (act) {
        const float4 wv = half ? m : meven;  // each lane stores its parity
        *(float4*)&memout[(((size_t)tp * NSL + e) * dim + d) * row +
                          half * SW + bq] = wv;
      }
    }

    if (save_state && act && half == 0) {
      const size_t so = ((size_t)e * dim + d) * SW + bq;
      *(float4*)&state[so] = s;
      *(float4*)&state[(size_t)NSL * dim * SW + so] = m;
    }
  }
}

// Final FC on t=15 (pair 7, odd half) of mem4: [8tp][8e][450][2][16].
__global__ __launch_bounds__(128) void fc_kernel(
    const float* __restrict__ mem4, const float* __restrict__ fc_w,
    const float* __restrict__ fc_b, float* __restrict__ out) {
  const int b  = threadIdx.x;
  const int e  = b >> 4;
  const int bl = b & 15;
  float a0 = fc_b[0], a1 = fc_b[1];
  const float* base = mem4 + ((size_t)7 * NSL + e) * 450 * 32;
  for (int d = 0; d < 450; ++d) {
    const float h = base[(size_t)d * 32 + SW + bl];
    a0 += fc_w[d] * h;
    a1 += fc_w[450 + d] * h;
  }
  out[b * 2 + 0] = a0;
  out[b * 2 + 1] = a1;
}

extern "C" void kernel_launch(void* const* d_in, const int* in_sizes, int n_in,
                              void* d_out, int out_size, void* d_ws,
                              size_t ws_size, hipStream_t stream) {
  (void)in_sizes; (void)n_in; (void)out_size; (void)ws_size;
  const float* x = (const float*)d_in[0];
  const float* w[5];
  const float* bias[5];
  const int* knn[5];
  for (int i = 0; i < 5; ++i) {
    w[i]    = (const float*)d_in[1 + 3 * i];
    bias[i] = (const float*)d_in[2 + 3 * i];
    knn[i]  = (const int*)d_in[3 + 3 * i];
  }
  const float* fc_w = (const float*)d_in[16];
  const float* fc_b = (const float*)d_in[17];
  float* out = (float*)d_out;

  static const int DIMS[5] = {7200, 3600, 1800, 900, 450};

  // Workspace (floats), 125.3 MB, paired layout [tp][8][d][2][16]:
  //   A  : 8tp*8*7200*32 = 14,745,600   (mem0 -> mem2 -> mem4)
  //   XB : 4tp*8*14400*32 = 14,745,600  (xT half-slab; later mem1 + mem3)
  //   S  : 2*8*7200*16  =  1,843,200    (layer-0 syn/mem carry, 16-wide)
  float* A  = (float*)d_ws;
  float* XB = A + 14745600;
  float* S  = XB + 14745600;

  float* mem0 = A;
  float* mem1 = XB;
  float* mem2 = A;
  float* mem3 = XB + 7372800;
  float* mem4 = A;

  // ---- Layer 0 in two 8-t (4-pair) stages ----
  for (int stage = 0; stage < 2; ++stage) {
    const int t0 = stage * 8;
    transpose_pair_kernel<<<dim3(IN_DIM / 64, B / 64, 8), 256, 0, stream>>>(
        x, XB, t0);
    // nblk=113/XCD, 2 passes covers 7232 >= 7200 neurons; grid 904 <= 1024.
    lcn_pair<4, 2><<<113 * NSL, 256, 0, stream>>>(
        XB, w[0], bias[0], knn[0], mem0 + (size_t)stage * 7372800, S,
        DIMS[0], IN_DIM, 113, /*load=*/stage, /*save=*/stage == 0);
  }

  // ---- Layers 1..4, 8 pairs each ----
  static const int NBLK[5] = {113, 113, 57, 29, 15};
  const float* src = mem0;
  float* dsts[4] = {mem1, mem2, mem3, mem4};
  for (int i = 1; i < 5; ++i) {
    lcn_pair<8, 1><<<NBLK[i] * NSL, 256, 0, stream>>>(
        src, w[i], bias[i], knn[i], dsts[i - 1], nullptr, DIMS[i],
        DIMS[i - 1], NBLK[i], 0, 0);
    src = dsts[i - 1];
  }

  fc_kernel<<<1, 128, 0, stream>>>(mem4, fc_w, fc_b, out);
}

// Round 12
// 344.792 us; speedup vs baseline: 1.4792x; 1.4792x over previous
//
#include <hip/hip_runtime.h>

#define ALPHA 0.9f
#define BETA  0.8f
#define K     25
#define B     128
#define T     16
#define IN_DIM 14400
#define NSL   8      // batch slices (= XCDs)
#define SW    16     // batch elems per slice
// bf16 paired-t row: [feature][2][16] bf16 = 64B; one row serves TWO timesteps.

using u16 = unsigned short;

static __device__ __forceinline__ u16 f2bf(float f) {
  union { float f; unsigned u; } c; c.f = f;
  const unsigned r = c.u + 0x7FFFu + ((c.u >> 16) & 1u);  // RTNE
  return (u16)(r >> 16);
}
static __device__ __forceinline__ float bf2f(u16 h) {
  union { unsigned u; float f; } c; c.u = ((unsigned)h) << 16;
  return c.f;
}

// ---------------------------------------------------------------------------
// Transpose one 8-t slab of x (B,T,IN) fp32 -> bf16 xTh[4tp][8e][IN][2][16].
// ---------------------------------------------------------------------------
__global__ __launch_bounds__(256) void transpose_bf_kernel(
    const float* __restrict__ x, u16* __restrict__ xTh, int t0) {
  __shared__ float tile[64][65];
  const int tl = blockIdx.z;            // local t 0..7
  const int t  = t0 + tl;
  const int i0 = blockIdx.x * 64;       // feature tile
  const int b0 = blockIdx.y * 64;       // batch tile
  const int tid = threadIdx.x;

  const int fi = (tid & 15) * 4;        // feature quad
  const int bi = tid >> 4;              // batch row 0..15
#pragma unroll
  for (int p = 0; p < 4; ++p) {
    const int b = bi + p * 16;
    const float4 v = *(const float4*)&x[(size_t)(b0 + b) * (T * IN_DIM) +
                                        (size_t)t * IN_DIM + i0 + fi];
    tile[fi + 0][b] = v.x;
    tile[fi + 1][b] = v.y;
    tile[fi + 2][b] = v.z;
    tile[fi + 3][b] = v.w;
  }
  __syncthreads();
  const int bq = (tid & 15) * 4;        // batch quad (0,4,..,60)
  const int fr = tid >> 4;              // feature row 0..15
  const int e  = (b0 + bq) >> 4;        // slice
  const int bl = bq & 15;               // 0,4,8,12
#pragma unroll
  for (int p = 0; p < 4; ++p) {
    const int f = fr + p * 16;
    ushort4 v;
    v.x = f2bf(tile[f][bq + 0]);
    v.y = f2bf(tile[f][bq + 1]);
    v.z = f2bf(tile[f][bq + 2]);
    v.w = f2bf(tile[f][bq + 3]);
    *(ushort4*)&xTh[(((size_t)(tl >> 1) * NSL + e) * IN_DIM + (i0 + f)) * 32 +
                    (tl & 1) * SW + bl] = v;
  }
}

// ---------------------------------------------------------------------------
// Fused LCN+LIF, bf16 t-PAIRED 64B rows. hsrc: [NTP][8][dprev][2][16] bf16,
// memout same shape for dim, state (fp32): [2][8][dim][16].
// 256 thr = 32 neurons x 8 lanes; lane = (t-parity half, batch quad).
// One wave-load (64 lanes x 8B) covers 8 FULL 64B rows serving 2 timesteps
// -> half the L2 row-requests of the round-10 layout at the SAME per-tp
// working set (bf16 halves bytes, pairing doubles t per row). LIF pair
// resolved via __shfl_xor(4); both halves redundantly track (s,m) in fp32.
// blockIdx%8 = slice = XCD; all grids <= 1024 = residency at LB(256,4).
// ---------------------------------------------------------------------------
template <int NTP, int NPASS>
__global__ __launch_bounds__(256, 4) void lcn_pair_bf(
    const u16* __restrict__ hsrc, const float* __restrict__ w,
    const float* __restrict__ bias, const int* __restrict__ knn,
    u16* __restrict__ memout, float* __restrict__ state,
    int dim, int dprev, int nblk, int load_state, int save_state) {
  const int e    = blockIdx.x & 7;        // slice -> XCD
  const int blk  = blockIdx.x >> 3;
  const int nl   = threadIdx.x >> 3;      // neuron in block (0..31)
  const int l8   = threadIdx.x & 7;
  const int half = l8 >> 2;               // t parity handled by this lane
  const int bq   = (l8 & 3) * 4;          // batch quad

#pragma unroll 1
  for (int p = 0; p < NPASS; ++p) {
    const int dd = (blk + p * nblk) * 32 + nl;
    const bool act = dd < dim;
    const int d = act ? dd : dim - 1;

    int   idx[K];
    float wr[K];
#pragma unroll
    for (int k = 0; k < K; ++k) {
      idx[k] = knn[d * K + k] * 32 + half * SW + bq;  // ushort elem offset
      wr[k]  = w[d * K + k];
    }
    const float bi = bias[d];

    float4 s = make_float4(0.f, 0.f, 0.f, 0.f);
    float4 m = make_float4(0.f, 0.f, 0.f, 0.f);
    if (load_state) {
      const size_t so = ((size_t)e * dim + d) * SW + bq;
      s = *(const float4*)&state[so];
      m = *(const float4*)&state[(size_t)NSL * dim * SW + so];
    }

    for (int tp = 0; tp < NTP; ++tp) {
      const u16* hp = hsrc + ((size_t)tp * NSL + e) * dprev * 32;
      ushort4 hv[13], hw[12];
#pragma unroll
      for (int j = 0; j < 13; ++j)
        hv[j] = *(const ushort4*)&hp[idx[j]];
#pragma unroll
      for (int j = 0; j < 12; ++j)
        hw[j] = *(const ushort4*)&hp[idx[13 + j]];
      float4 a0 = make_float4(bi, bi, bi, bi);
      float4 a1 = make_float4(0.f, 0.f, 0.f, 0.f);
#pragma unroll
      for (int j = 0; j < 13; ++j) {
        const float wk = wr[j];
        if (j & 1) {
          a1.x = fmaf(wk, bf2f(hv[j].x), a1.x);
          a1.y = fmaf(wk, bf2f(hv[j].y), a1.y);
          a1.z = fmaf(wk, bf2f(hv[j].z), a1.z);
          a1.w = fmaf(wk, bf2f(hv[j].w), a1.w);
        } else {
          a0.x = fmaf(wk, bf2f(hv[j].x), a0.x);
          a0.y = fmaf(wk, bf2f(hv[j].y), a0.y);
          a0.z = fmaf(wk, bf2f(hv[j].z), a0.z);
          a0.w = fmaf(wk, bf2f(hv[j].w), a0.w);
        }
      }
#pragma unroll
      for (int j = 0; j < 12; ++j) {
        const float wk = wr[13 + j];
        if (j & 1) {
          a1.x = fmaf(wk, bf2f(hw[j].x), a1.x);
          a1.y = fmaf(wk, bf2f(hw[j].y), a1.y);
          a1.z = fmaf(wk, bf2f(hw[j].z), a1.z);
          a1.w = fmaf(wk, bf2f(hw[j].w), a1.w);
        } else {
          a0.x = fmaf(wk, bf2f(hw[j].x), a0.x);
          a0.y = fmaf(wk, bf2f(hw[j].y), a0.y);
          a0.z = fmaf(wk, bf2f(hw[j].z), a0.z);
          a0.w = fmaf(wk, bf2f(hw[j].w), a0.w);
        }
      }
      float4 acc;
      acc.x = a0.x + a1.x;
      acc.y = a0.y + a1.y;
      acc.z = a0.z + a1.z;
      acc.w = a0.w + a1.w;
      // exchange halves: each lane obtains the other parity's pre-activation
      float4 oth;
      oth.x = __shfl_xor(acc.x, 4, 64);
      oth.y = __shfl_xor(acc.y, 4, 64);
      oth.z = __shfl_xor(acc.z, 4, 64);
      oth.w = __shfl_xor(acc.w, 4, 64);
      const float4 pre0 = half ? oth : acc;  // t even
      const float4 pre1 = half ? acc : oth;  // t odd
      // LIF t-even (reset from PREVIOUS membrane)
      s.x = ALPHA * s.x + pre0.x;
      s.y = ALPHA * s.y + pre0.y;
      s.z = ALPHA * s.z + pre0.z;
      s.w = ALPHA * s.w + pre0.w;
      float4 meven;
      meven.x = BETA * m.x + s.x - ((m.x > 1.0f) ? 1.0f : 0.0f);
      meven.y = BETA * m.y + s.y - ((m.y > 1.0f) ? 1.0f : 0.0f);
      meven.z = BETA * m.z + s.z - ((m.z > 1.0f) ? 1.0f : 0.0f);
      meven.w = BETA * m.w + s.w - ((m.w > 1.0f) ? 1.0f : 0.0f);
      // LIF t-odd
      s.x = ALPHA * s.x + pre1.x;
      s.y = ALPHA * s.y + pre1.y;
      s.z = ALPHA * s.z + pre1.z;
      s.w = ALPHA * s.w + pre1.w;
      m.x = BETA * meven.x + s.x - ((meven.x > 1.0f) ? 1.0f : 0.0f);
      m.y = BETA * meven.y + s.y - ((meven.y > 1.0f) ? 1.0f : 0.0f);
      m.z = BETA * meven.z + s.z - ((meven.z > 1.0f) ? 1.0f : 0.0f);
      m.w = BETA * meven.w + s.w - ((meven.w > 1.0f) ? 1.0f : 0.0f);
      if (act) {
        const float4 wv = half ? m : meven;  // each lane stores its parity
        ushort4 ov;
        ov.x = f2bf(wv.x);
        ov.y = f2bf(wv.y);
        ov.z = f2bf(wv.z);
        ov.w = f2bf(wv.w);
        *(ushort4*)&memout[(((size_t)tp * NSL + e) * dim + d) * 32 +
                           half * SW + bq] = ov;
      }
    }

    if (save_state && act && half == 0) {
      const size_t so = ((size_t)e * dim + d) * SW + bq;
      *(float4*)&state[so] = s;
      *(float4*)&state[(size_t)NSL * dim * SW + so] = m;
    }
  }
}

// Final FC on t=15 (pair 7, odd half) of mem4: [8tp][8e][450][2][16] bf16.
__global__ __launch_bounds__(128) void fc_kernel(
    const u16* __restrict__ mem4, const float* __restrict__ fc_w,
    const float* __restrict__ fc_b, float* __restrict__ out) {
  const int b  = threadIdx.x;
  const int e  = b >> 4;
  const int bl = b & 15;
  float a0 = fc_b[0], a1 = fc_b[1];
  const u16* base = mem4 + ((size_t)7 * NSL + e) * 450 * 32;
  for (int d = 0; d < 450; ++d) {
    const float h = bf2f(base[(size_t)d * 32 + SW + bl]);
    a0 += fc_w[d] * h;
    a1 += fc_w[450 + d] * h;
  }
  out[b * 2 + 0] = a0;
  out[b * 2 + 1] = a1;
}

extern "C" void kernel_launch(void* const* d_in, const int* in_sizes, int n_in,
                              void* d_out, int out_size, void* d_ws,
                              size_t ws_size, hipStream_t stream) {
  (void)in_sizes; (void)n_in; (void)out_size; (void)ws_size;
  const float* x = (const float*)d_in[0];
  const float* w[5];
  const float* bias[5];
  const int* knn[5];
  for (int i = 0; i < 5; ++i) {
    w[i]    = (const float*)d_in[1 + 3 * i];
    bias[i] = (const float*)d_in[2 + 3 * i];
    knn[i]  = (const int*)d_in[3 + 3 * i];
  }
  const float* fc_w = (const float*)d_in[16];
  const float* fc_b = (const float*)d_in[17];
  float* out = (float*)d_out;

  static const int DIMS[5] = {7200, 3600, 1800, 900, 450};

  // Workspace: bf16 traces (paired layout [tp][8][d][2][16]) + fp32 state.
  //   A  : 8tp*8*7200*32 u16 = 14,745,600 u16 = 29.5 MB (mem0 -> mem2 -> mem4)
  //   XB : 4tp*8*14400*32 u16 = 14,745,600 u16 (xT half-slab; later mem1+mem3)
  //   S  : 2*8*7200*16 fp32 = 1,843,200 floats (layer-0 syn/mem carry)
  u16* A  = (u16*)d_ws;
  u16* XB = A + 14745600;
  float* S = (float*)(XB + 14745600);

  u16* mem0 = A;
  u16* mem1 = XB;
  u16* mem2 = A;
  u16* mem3 = XB + 7372800;
  u16* mem4 = A;

  // ---- Layer 0 in two 8-t (4-pair) stages ----
  for (int stage = 0; stage < 2; ++stage) {
    const int t0 = stage * 8;
    transpose_bf_kernel<<<dim3(IN_DIM / 64, B / 64, 8), 256, 0, stream>>>(
        x, XB, t0);
    // 113 blocks/XCD x 2 passes covers 7232 >= 7200 neurons; grid 904 <= 1024.
    lcn_pair_bf<4, 2><<<113 * NSL, 256, 0, stream>>>(
        XB, w[0], bias[0], knn[0], mem0 + (size_t)stage * 7372800, S,
        DIMS[0], IN_DIM, 113, /*load=*/stage, /*save=*/stage == 0);
  }

  // ---- Layers 1..4, 8 pairs each ----
  static const int NBLK[5] = {113, 113, 57, 29, 15};
  const u16* src = mem0;
  u16* dsts[4] = {mem1, mem2, mem3, mem4};
  for (int i = 1; i < 5; ++i) {
    lcn_pair_bf<8, 1><<<NBLK[i] * NSL, 256, 0, stream>>>(
        src, w[i], bias[i], knn[i], dsts[i - 1], nullptr, DIMS[i],
        DIMS[i - 1], NBLK[i], 0, 0);
    src = dsts[i - 1];
  }

  fc_kernel<<<1, 128, 0, stream>>>(mem4, fc_w, fc_b, out);
}

// Round 13
// 335.960 us; speedup vs baseline: 1.5180x; 1.0263x over previous
//
#include <hip/hip_runtime.h>

#define ALPHA 0.9f
#define BETA  0.8f
#define K     25
#define B     128
#define T     16
#define IN_DIM 14400
#define NSL   8      // batch slices (= XCDs)
#define SW    16     // batch elems per slice
#define CF    96     // features per transpose tile
#define NCH   150    // IN_DIM / CF
// bf16 paired-t row: [feature][2][16] bf16 = 64B; one row serves TWO timesteps.

using u16 = unsigned short;

static __device__ __forceinline__ u16 f2bf(float f) {
  union { float f; unsigned u; } c; c.f = f;
  const unsigned r = c.u + 0x7FFFu + ((c.u >> 16) & 1u);  // RTNE
  return (u16)(r >> 16);
}
static __device__ __forceinline__ float bf2f(u16 h) {
  union { unsigned u; float f; } c; c.u = ((unsigned)h) << 16;
  return c.f;
}

// ---------------------------------------------------------------------------
// Slice-pinned pair-complete transpose. x (B,T,IN) fp32 slab [t0,t0+8) ->
// bf16 xTh[4tp][8e][IN][2][16]. blockIdx%8 = slice e (grid 1024 = residency
// at LB(256,4) -> exact XCD pinning). Each tile: BOTH parities of one t-pair
// x 96 features for slice e -> every 64B output row (and every 128B line,
// via consecutive features) is written COMPLETE by ONE block on the OWNING
// XCD. Kills the round-12 cross-XCD partial-line RMW storm.
// ---------------------------------------------------------------------------
__global__ __launch_bounds__(256, 4) void transpose_pair_pinned(
    const float* __restrict__ x, u16* __restrict__ xTh, int t0, int slots) {
  __shared__ float lds[CF][33];
  const int e    = blockIdx.x & 7;
  const int slot = blockIdx.x >> 3;
  const int tid  = threadIdx.x;
  const int rid  = tid >> 3;        // 0..31 = output col (parity*16 + bl)
  const int fq   = tid & 7;
  const int tpar = rid >> 4;        // t parity
  const int bl   = rid & 15;
  const int b    = e * 16 + bl;

  const int ntiles = 4 * NCH;       // t-pairs x feature chunks
  for (int ti = slot; ti < ntiles; ti += slots) {
    const int tp = ti / NCH;        // tp-major: co-resident blocks cluster in t
    const int ch = ti - tp * NCH;
    const int i0 = ch * CF;
    const int t  = t0 + tp * 2 + tpar;
    const float* xr = x + ((size_t)b * T + t) * IN_DIM + i0;
#pragma unroll
    for (int pf = 0; pf < CF / 32; ++pf) {
      const float4 v = *(const float4*)&xr[pf * 32 + fq * 4];
      lds[pf * 32 + fq * 4 + 0][rid] = v.x;
      lds[pf * 32 + fq * 4 + 1][rid] = v.y;
      lds[pf * 32 + fq * 4 + 2][rid] = v.z;
      lds[pf * 32 + fq * 4 + 3][rid] = v.w;
    }
    __syncthreads();
    // write: row f = 32 u16 = 64B, 8 threads/row, 512B contiguous per wave
#pragma unroll
    for (int wp = 0; wp < CF / 32; ++wp) {
      const int f = wp * 32 + rid;  // rid = feature row here
      ushort4 ov;
      ov.x = f2bf(lds[f][fq * 4 + 0]);
      ov.y = f2bf(lds[f][fq * 4 + 1]);
      ov.z = f2bf(lds[f][fq * 4 + 2]);
      ov.w = f2bf(lds[f][fq * 4 + 3]);
      *(ushort4*)&xTh[(((size_t)tp * NSL + e) * IN_DIM + (i0 + f)) * 32 +
                      fq * 4] = ov;
    }
    __syncthreads();
  }
}

// ---------------------------------------------------------------------------
// Fused LCN+LIF, bf16 t-PAIRED 64B rows (unchanged from round 12 - proven).
// ---------------------------------------------------------------------------
template <int NTP, int NPASS>
__global__ __launch_bounds__(256, 4) void lcn_pair_bf(
    const u16* __restrict__ hsrc, const float* __restrict__ w,
    const float* __restrict__ bias, const int* __restrict__ knn,
    u16* __restrict__ memout, float* __restrict__ state,
    int dim, int dprev, int nblk, int load_state, int save_state) {
  const int e    = blockIdx.x & 7;        // slice -> XCD
  const int blk  = blockIdx.x >> 3;
  const int nl   = threadIdx.x >> 3;      // neuron in block (0..31)
  const int l8   = threadIdx.x & 7;
  const int half = l8 >> 2;               // t parity handled by this lane
  const int bq   = (l8 & 3) * 4;          // batch quad

#pragma unroll 1
  for (int p = 0; p < NPASS; ++p) {
    const int dd = (blk + p * nblk) * 32 + nl;
    const bool act = dd < dim;
    const int d = act ? dd : dim - 1;

    int   idx[K];
    float wr[K];
#pragma unroll
    for (int k = 0; k < K; ++k) {
      idx[k] = knn[d * K + k] * 32 + half * SW + bq;  // ushort elem offset
      wr[k]  = w[d * K + k];
    }
    const float bi = bias[d];

    float4 s = make_float4(0.f, 0.f, 0.f, 0.f);
    float4 m = make_float4(0.f, 0.f, 0.f, 0.f);
    if (load_state) {
      const size_t so = ((size_t)e * dim + d) * SW + bq;
      s = *(const float4*)&state[so];
      m = *(const float4*)&state[(size_t)NSL * dim * SW + so];
    }

    for (int tp = 0; tp < NTP; ++tp) {
      const u16* hp = hsrc + ((size_t)tp * NSL + e) * dprev * 32;
      ushort4 hv[13], hw[12];
#pragma unroll
      for (int j = 0; j < 13; ++j)
        hv[j] = *(const ushort4*)&hp[idx[j]];
#pragma unroll
      for (int j = 0; j < 12; ++j)
        hw[j] = *(const ushort4*)&hp[idx[13 + j]];
      float4 a0 = make_float4(bi, bi, bi, bi);
      float4 a1 = make_float4(0.f, 0.f, 0.f, 0.f);
#pragma unroll
      for (int j = 0; j < 13; ++j) {
        const float wk = wr[j];
        if (j & 1) {
          a1.x = fmaf(wk, bf2f(hv[j].x), a1.x);
          a1.y = fmaf(wk, bf2f(hv[j].y), a1.y);
          a1.z = fmaf(wk, bf2f(hv[j].z), a1.z);
          a1.w = fmaf(wk, bf2f(hv[j].w), a1.w);
        } else {
          a0.x = fmaf(wk, bf2f(hv[j].x), a0.x);
          a0.y = fmaf(wk, bf2f(hv[j].y), a0.y);
          a0.z = fmaf(wk, bf2f(hv[j].z), a0.z);
          a0.w = fmaf(wk, bf2f(hv[j].w), a0.w);
        }
      }
#pragma unroll
      for (int j = 0; j < 12; ++j) {
        const float wk = wr[13 + j];
        if (j & 1) {
          a1.x = fmaf(wk, bf2f(hw[j].x), a1.x);
          a1.y = fmaf(wk, bf2f(hw[j].y), a1.y);
          a1.z = fmaf(wk, bf2f(hw[j].z), a1.z);
          a1.w = fmaf(wk, bf2f(hw[j].w), a1.w);
        } else {
          a0.x = fmaf(wk, bf2f(hw[j].x), a0.x);
          a0.y = fmaf(wk, bf2f(hw[j].y), a0.y);
          a0.z = fmaf(wk, bf2f(hw[j].z), a0.z);
          a0.w = fmaf(wk, bf2f(hw[j].w), a0.w);
        }
      }
      float4 acc;
      acc.x = a0.x + a1.x;
      acc.y = a0.y + a1.y;
      acc.z = a0.z + a1.z;
      acc.w = a0.w + a1.w;
      // exchange halves: each lane obtains the other parity's pre-activation
      float4 oth;
      oth.x = __shfl_xor(acc.x, 4, 64);
      oth.y = __shfl_xor(acc.y, 4, 64);
      oth.z = __shfl_xor(acc.z, 4, 64);
      oth.w = __shfl_xor(acc.w, 4, 64);
      const float4 pre0 = half ? oth : acc;  // t even
      const float4 pre1 = half ? acc : oth;  // t odd
      // LIF t-even (reset from PREVIOUS membrane)
      s.x = ALPHA * s.x + pre0.x;
      s.y = ALPHA * s.y + pre0.y;
      s.z = ALPHA * s.z + pre0.z;
      s.w = ALPHA * s.w + pre0.w;
      float4 meven;
      meven.x = BETA * m.x + s.x - ((m.x > 1.0f) ? 1.0f : 0.0f);
      meven.y = BETA * m.y + s.y - ((m.y > 1.0f) ? 1.0f : 0.0f);
      meven.z = BETA * m.z + s.z - ((m.z > 1.0f) ? 1.0f : 0.0f);
      meven.w = BETA * m.w + s.w - ((m.w > 1.0f) ? 1.0f : 0.0f);
      // LIF t-odd
      s.x = ALPHA * s.x + pre1.x;
      s.y = ALPHA * s.y + pre1.y;
      s.z = ALPHA * s.z + pre1.z;
      s.w = ALPHA * s.w + pre1.w;
      m.x = BETA * meven.x + s.x - ((meven.x > 1.0f) ? 1.0f : 0.0f);
      m.y = BETA * meven.y + s.y - ((meven.y > 1.0f) ? 1.0f : 0.0f);
      m.z = BETA * meven.z + s.z - ((meven.z > 1.0f) ? 1.0f : 0.0f);
      m.w = BETA * meven.w + s.w - ((meven.w > 1.0f) ? 1.0f : 0.0f);
      if (act) {
        const float4 wv = half ? m : meven;  // each lane stores its parity
        ushort4 ov;
        ov.x = f2bf(wv.x);
        ov.y = f2bf(wv.y);
        ov.z = f2bf(wv.z);
        ov.w = f2bf(wv.w);
        *(ushort4*)&memout[(((size_t)tp * NSL + e) * dim + d) * 32 +
                           half * SW + bq] = ov;
      }
    }

    if (save_state && act && half == 0) {
      const size_t so = ((size_t)e * dim + d) * SW + bq;
      *(float4*)&state[so] = s;
      *(float4*)&state[(size_t)NSL * dim * SW + so] = m;
    }
  }
}

// Final FC on t=15 (pair 7, odd half) of mem4: [8tp][8e][450][2][16] bf16.
__global__ __launch_bounds__(128) void fc_kernel(
    const u16* __restrict__ mem4, const float* __restrict__ fc_w,
    const float* __restrict__ fc_b, float* __restrict__ out) {
  const int b  = threadIdx.x;
  const int e  = b >> 4;
  const int bl = b & 15;
  float a0 = fc_b[0], a1 = fc_b[1];
  const u16* base = mem4 + ((size_t)7 * NSL + e) * 450 * 32;
  for (int d = 0; d < 450; ++d) {
    const float h = bf2f(base[(size_t)d * 32 + SW + bl]);
    a0 += fc_w[d] * h;
    a1 += fc_w[450 + d] * h;
  }
  out[b * 2 + 0] = a0;
  out[b * 2 + 1] = a1;
}

extern "C" void kernel_launch(void* const* d_in, const int* in_sizes, int n_in,
                              void* d_out, int out_size, void* d_ws,
                              size_t ws_size, hipStream_t stream) {
  (void)in_sizes; (void)n_in; (void)out_size; (void)ws_size;
  const float* x = (const float*)d_in[0];
  const float* w[5];
  const float* bias[5];
  const int* knn[5];
  for (int i = 0; i < 5; ++i) {
    w[i]    = (const float*)d_in[1 + 3 * i];
    bias[i] = (const float*)d_in[2 + 3 * i];
    knn[i]  = (const int*)d_in[3 + 3 * i];
  }
  const float* fc_w = (const float*)d_in[16];
  const float* fc_b = (const float*)d_in[17];
  float* out = (float*)d_out;

  static const int DIMS[5] = {7200, 3600, 1800, 900, 450};

  // Workspace: bf16 traces (paired layout [tp][8][d][2][16]) + fp32 state.
  //   A  : 8tp*8*7200*32 u16 = 14,745,600 u16 = 29.5 MB (mem0 -> mem2 -> mem4)
  //   XB : 4tp*8*14400*32 u16 = 14,745,600 u16 (xT half-slab; later mem1+mem3)
  //   S  : 2*8*7200*16 fp32 = 1,843,200 floats (layer-0 syn/mem carry)
  u16* A  = (u16*)d_ws;
  u16* XB = A + 14745600;
  float* S = (float*)(XB + 14745600);

  u16* mem0 = A;
  u16* mem1 = XB;
  u16* mem2 = A;
  u16* mem3 = XB + 7372800;
  u16* mem4 = A;

  // ---- Layer 0 in two 8-t (4-pair) stages ----
  for (int stage = 0; stage < 2; ++stage) {
    const int t0 = stage * 8;
    transpose_pair_pinned<<<128 * NSL, 256, 0, stream>>>(x, XB, t0, 128);
    // 113 blocks/XCD x 2 passes covers 7232 >= 7200 neurons; grid 904 <= 1024.
    lcn_pair_bf<4, 2><<<113 * NSL, 256, 0, stream>>>(
        XB, w[0], bias[0], knn[0], mem0 + (size_t)stage * 7372800, S,
        DIMS[0], IN_DIM, 113, /*load=*/stage, /*save=*/stage == 0);
  }

  // ---- Layers 1..4, 8 pairs each ----
  static const int NBLK[5] = {113, 113, 57, 29, 15};
  const u16* src = mem0;
  u16* dsts[4] = {mem1, mem2, mem3, mem4};
  for (int i = 1; i < 5; ++i) {
    lcn_pair_bf<8, 1><<<NBLK[i] * NSL, 256, 0, stream>>>(
        src, w[i], bias[i], knn[i], dsts[i - 1], nullptr, DIMS[i],
        DIMS[i - 1], NBLK[i], 0, 0);
    src = dsts[i - 1];
  }

  fc_kernel<<<1, 128, 0, stream>>>(mem4, fc_w, fc_b, out);
}